// Round 3
// baseline (2073.845 us; speedup 1.0000x reference)
//
#include <hip/hip_runtime.h>
#include <hip/hip_bf16.h>
#include <math.h>

typedef __hip_bfloat16 bf16;
typedef __attribute__((ext_vector_type(8))) __bf16 bf16x8;
typedef __attribute__((ext_vector_type(4))) float floatx4;

#define CDIM 192
#define N_WINDOWS 2048
#define ATT_SCALE 0.17677669529663687f   // 1/sqrt(32)

__device__ inline float toF(float v) { return v; }
__device__ inline float toF(bf16 v) { return __bfloat162float(v); }

// windowed (wi, n, col) -> natural flat element index
__device__ inline long nat_index(int wi, int n, int col) {
    int wb = wi & 15, hb = (wi >> 4) & 15, tb = (wi >> 8) & 3, bb = wi >> 10;
    int t  = tb * 2 + (n >> 6);
    int hh = hb * 8 + ((n >> 3) & 7);
    int w  = wb * 8 + (n & 7);
    return ((((long)(bb * 8 + t)) * 128 + hh) * 128 + w) * CDIM + col;
}

// branch-free erf, Abramowitz-Stegun 7.1.26, |err|<=1.5e-7
__device__ inline float erf_as(float x) {
    float ax = fabsf(x);
    float t = 1.0f / (1.0f + 0.3275911f * ax);
    float p = t * (0.254829592f + t * (-0.284496736f + t * (1.421413741f +
              t * (-1.453152027f + t * 1.061405429f))));
    float e = 1.0f - p * __expf(-ax * ax);
    return copysignf(e, x);
}

// ---------------------------------------------------------------------------
// Convert all weights f32 -> bf16 into ws: [qkv 110592][proj 36864][fc1 147456][fc2 147456]
// ---------------------------------------------------------------------------
__launch_bounds__(256)
__global__ void convert_weights(const float* __restrict__ qkv_w, const float* __restrict__ proj_w,
                                const float* __restrict__ fc1_w, const float* __restrict__ fc2_w,
                                bf16* __restrict__ dst) {
    long e = ((long)blockIdx.x * 256 + threadIdx.x) * 8;
    const float* src; long off;
    if (e < 110592)       { src = qkv_w;  off = e; }
    else if (e < 147456)  { src = proj_w; off = e - 110592; }
    else if (e < 294912)  { src = fc1_w;  off = e - 147456; }
    else                  { src = fc2_w;  off = e - 294912; }
    float4 a = *(const float4*)(src + off);
    float4 b = *(const float4*)(src + off + 4);
    bf16x8 o;
    o[0] = (__bf16)a.x; o[1] = (__bf16)a.y; o[2] = (__bf16)a.z; o[3] = (__bf16)a.w;
    o[4] = (__bf16)b.x; o[5] = (__bf16)b.y; o[6] = (__bf16)b.z; o[7] = (__bf16)b.w;
    *(bf16x8*)(dst + e) = o;
}

// ---------------------------------------------------------------------------
// LayerNorm (ln1 only now), one wave per row of 192, windowed gather.
// ---------------------------------------------------------------------------
__launch_bounds__(256)
__global__ void ln_kernel(const float* __restrict__ x, const float* __restrict__ g,
                          const float* __restrict__ bta, bf16* __restrict__ out,
                          int wi_base) {
    int row = blockIdx.x * 4 + (threadIdx.x >> 6);
    int lane = threadIdx.x & 63;
    long src = nat_index(wi_base + (row >> 7), row & 127, 0);
    float v0 = x[src + lane];
    float v1 = x[src + lane + 64];
    float v2 = x[src + lane + 128];
    float s = v0 + v1 + v2;
    float sq = v0 * v0 + v1 * v1 + v2 * v2;
    #pragma unroll
    for (int o = 32; o > 0; o >>= 1) { s += __shfl_xor(s, o); sq += __shfl_xor(sq, o); }
    float mean = s * (1.0f / 192.0f);
    float var  = sq * (1.0f / 192.0f) - mean * mean;
    float rstd = rsqrtf(fmaxf(var, 0.0f) + 1e-5f);
    long dst = (long)row * CDIM;
    out[dst + lane]       = __float2bfloat16((v0 - mean) * rstd * g[lane]       + bta[lane]);
    out[dst + lane + 64]  = __float2bfloat16((v1 - mean) * rstd * g[lane + 64]  + bta[lane + 64]);
    out[dst + lane + 128] = __float2bfloat16((v2 - mean) * rstd * g[lane + 128] + bta[lane + 128]);
}

// ---------------------------------------------------------------------------
// GEMM: C[M,N] = A[M,K](bf16) @ W[N,K]^T(bf16). BM=128, BN=64, BK=32.
// LDS stride 40 (pads 16-bank row stride -> conflict-free frag reads).
// ---------------------------------------------------------------------------
template<typename Epi>
__launch_bounds__(256)
__global__ void gemm_bt(const bf16* __restrict__ A, const bf16* __restrict__ Wt,
                        int K, Epi epi) {
    __shared__ __align__(16) bf16 sA[128 * 40];
    __shared__ __align__(16) bf16 sW[64 * 40];
    const int tid = threadIdx.x;
    const int lane = tid & 63;
    const int wv = tid >> 6;
    const int colb = lane & 15, quad = lane >> 4;
    const int m0 = blockIdx.x * 128;
    const int n0 = blockIdx.y * 64;

    floatx4 acc[2][4] = {};

    for (int k0 = 0; k0 < K; k0 += 32) {
        #pragma unroll
        for (int i = 0; i < 2; ++i) {   // A tile 128x32
            int idx = tid + i * 256;
            int row = idx >> 2, kc = (idx & 3) << 3;
            *(uint4*)(&sA[row * 40 + kc]) =
                *(const uint4*)(A + (long)(m0 + row) * K + k0 + kc);
        }
        {   // W tile 64x32
            int row = tid >> 2, kc = (tid & 3) << 3;
            *(uint4*)(&sW[row * 40 + kc]) =
                *(const uint4*)(Wt + (long)(n0 + row) * K + k0 + kc);
        }
        __syncthreads();
        bf16x8 aF[2], bF[4];
        #pragma unroll
        for (int rt = 0; rt < 2; ++rt)
            aF[rt] = *(const bf16x8*)(&sA[(wv * 32 + rt * 16 + colb) * 40 + quad * 8]);
        #pragma unroll
        for (int ct = 0; ct < 4; ++ct)
            bF[ct] = *(const bf16x8*)(&sW[(ct * 16 + colb) * 40 + quad * 8]);
        #pragma unroll
        for (int rt = 0; rt < 2; ++rt)
            #pragma unroll
            for (int ct = 0; ct < 4; ++ct)
                acc[rt][ct] = __builtin_amdgcn_mfma_f32_16x16x32_bf16(aF[rt], bF[ct], acc[rt][ct], 0, 0, 0);
        __syncthreads();
    }
    #pragma unroll
    for (int rt = 0; rt < 2; ++rt)
        #pragma unroll
        for (int ct = 0; ct < 4; ++ct)
            #pragma unroll
            for (int r = 0; r < 4; ++r) {
                int row = m0 + wv * 32 + rt * 16 + quad * 4 + r;
                int col = n0 + ct * 16 + colb;
                epi(row, col, acc[rt][ct][r]);
            }
}

// ------------------------------ epilogues ----------------------------------
struct EpiQKV {
    const float* bias; bf16 *q, *k, *v;
    __device__ void operator()(int row, int col, float val) const {
        val += bias[col];
        int wi = row >> 7, n = row & 127;
        int part = col / 192, rem = col - part * 192;
        int h = rem >> 5, d = rem & 31;
        long base = (long)(wi * 6 + h);
        if (part == 0)      q[(base * 128 + n) * 32 + d] = __float2bfloat16(val);
        else if (part == 1) k[(base * 128 + n) * 32 + d] = __float2bfloat16(val);
        else                v[(base * 32 + d) * 128 + n] = __float2bfloat16(val); // transposed
    }
};

struct EpiProj {   // x2(local, windowed) = attn_proj + x(natural, global)
    const float* bias; const float* x; bf16* x2; int wi_base;
    __device__ void operator()(int row, int col, float val) const {
        val += bias[col];
        long nat = nat_index(wi_base + (row >> 7), row & 127, col);
        x2[(long)row * CDIM + col] = __float2bfloat16(val + x[nat]);
    }
};

// ---------------------------------------------------------------------------
// Attention: one block per (local window, head). QK^T -> softmax -> PV.
// Padded LDS strides: sQ/sK 40, sVT/sP 136.
// ---------------------------------------------------------------------------
__device__ inline float rel_bias(const float* bt, int h, int n, int m) {
    int tn = n >> 6, hn = (n >> 3) & 7, wn = n & 7;
    int tm = m >> 6, hm = (m >> 3) & 7, wm = m & 7;
    int idx = (tn - tm + 1) * 225 + (hn - hm + 7) * 15 + (wn - wm + 7);
    return bt[idx * 6 + h];
}

__launch_bounds__(256)
__global__ void attn_kernel(const bf16* __restrict__ q, const bf16* __restrict__ k,
                            const bf16* __restrict__ vT, const float* __restrict__ bt,
                            bf16* __restrict__ out) {
    __shared__ __align__(16) bf16 sQ[128 * 40];
    __shared__ __align__(16) bf16 sK[128 * 40];
    __shared__ __align__(16) bf16 sVT[32 * 136];
    __shared__ __align__(16) bf16 sP[128 * 136];
    const int blk = blockIdx.x;           // wi_local*6 + h
    const int h = blk % 6;
    const int wi = blk / 6;
    const int tid = threadIdx.x, lane = tid & 63, wv = tid >> 6;
    const bf16* qg = q + (long)blk * 4096;
    const bf16* kg = k + (long)blk * 4096;
    const bf16* vg = vT + (long)blk * 4096;
    #pragma unroll
    for (int i = 0; i < 2; ++i) {
        int v = tid + i * 256;            // 512 vec8 each
        int r4 = v >> 2, kc = (v & 3) << 3;
        *(uint4*)(&sQ[r4 * 40 + kc])  = *(const uint4*)(qg + v * 8);
        *(uint4*)(&sK[r4 * 40 + kc])  = *(const uint4*)(kg + v * 8);
        int rv = v >> 4, cv = (v & 15) << 3;
        *(uint4*)(&sVT[rv * 136 + cv]) = *(const uint4*)(vg + v * 8);
    }
    __syncthreads();

    const int mrow = wv * 32;
    const int colb = lane & 15, quad = lane >> 4;
    floatx4 zero = {0.f, 0.f, 0.f, 0.f};
    floatx4 s[2][8];
    bf16x8 aF[2];
    #pragma unroll
    for (int rt = 0; rt < 2; ++rt)
        aF[rt] = *(const bf16x8*)(&sQ[(mrow + rt * 16 + colb) * 40 + quad * 8]);
    #pragma unroll
    for (int ct = 0; ct < 8; ++ct) {
        bf16x8 bF = *(const bf16x8*)(&sK[(ct * 16 + colb) * 40 + quad * 8]);
        #pragma unroll
        for (int rt = 0; rt < 2; ++rt)
            s[rt][ct] = __builtin_amdgcn_mfma_f32_16x16x32_bf16(aF[rt], bF, zero, 0, 0, 0);
    }
    #pragma unroll
    for (int rt = 0; rt < 2; ++rt) {
        #pragma unroll
        for (int r = 0; r < 4; ++r) {
            int n = mrow + rt * 16 + quad * 4 + r;
            float vals[8];
            float mx = -1e30f;
            #pragma unroll
            for (int ct = 0; ct < 8; ++ct) {
                float v = s[rt][ct][r] * ATT_SCALE + rel_bias(bt, h, n, ct * 16 + colb);
                vals[ct] = v; mx = fmaxf(mx, v);
            }
            #pragma unroll
            for (int o = 1; o < 16; o <<= 1) mx = fmaxf(mx, __shfl_xor(mx, o));
            float sum = 0.f;
            #pragma unroll
            for (int ct = 0; ct < 8; ++ct) { vals[ct] = __expf(vals[ct] - mx); sum += vals[ct]; }
            #pragma unroll
            for (int o = 1; o < 16; o <<= 1) sum += __shfl_xor(sum, o);
            float inv = 1.0f / sum;
            #pragma unroll
            for (int ct = 0; ct < 8; ++ct)
                sP[n * 136 + ct * 16 + colb] = __float2bfloat16(vals[ct] * inv);
        }
    }
    __syncthreads();
    floatx4 o[2][2] = {};
    #pragma unroll
    for (int kk = 0; kk < 4; ++kk) {
        bf16x8 aP[2];
        #pragma unroll
        for (int rt = 0; rt < 2; ++rt)
            aP[rt] = *(const bf16x8*)(&sP[(mrow + rt * 16 + colb) * 136 + kk * 32 + quad * 8]);
        #pragma unroll
        for (int ct = 0; ct < 2; ++ct) {
            bf16x8 bV = *(const bf16x8*)(&sVT[(ct * 16 + colb) * 136 + kk * 32 + quad * 8]);
            #pragma unroll
            for (int rt = 0; rt < 2; ++rt)
                o[rt][ct] = __builtin_amdgcn_mfma_f32_16x16x32_bf16(aP[rt], bV, o[rt][ct], 0, 0, 0);
        }
    }
    #pragma unroll
    for (int rt = 0; rt < 2; ++rt)
        #pragma unroll
        for (int ct = 0; ct < 2; ++ct)
            #pragma unroll
            for (int r = 0; r < 4; ++r) {
                int n = mrow + rt * 16 + quad * 4 + r;
                out[((long)(wi * 128 + n)) * CDIM + h * 32 + ct * 16 + colb] =
                    __float2bfloat16(o[rt][ct][r]);
            }
}

// ---------------------------------------------------------------------------
// Fused MLP: out(natural) = x2 + fc2(gelu(fc1(LN(x2)))). 64 rows/block.
// Stage1: h[64x768] in 3 chunks of 256 cols; each wave owns 16 rows.
// ---------------------------------------------------------------------------
__launch_bounds__(256)
__global__ void mlp_kernel(const bf16* __restrict__ x2, const float* __restrict__ g,
                           const float* __restrict__ b, const bf16* __restrict__ w1,
                           const float* __restrict__ b1, const bf16* __restrict__ w2,
                           const float* __restrict__ b2, float* __restrict__ out,
                           int wi_base) {
    __shared__ __align__(16) bf16 sX[64 * 200];    // normalized input, stride 200
    __shared__ __align__(16) bf16 sH[64 * 264];    // gelu(h) chunk, stride 264
    __shared__ __align__(16) bf16 sW[256 * 40];    // weight staging, stride 40
    const int tid = threadIdx.x, lane = tid & 63, wv = tid >> 6;
    const int colb = lane & 15, quad = lane >> 4;
    const long row0 = (long)blockIdx.x * 64;       // slab-local

    // ---- LN: lane handles row (wv*16+colb), col segment quad*48..+48
    {
        int rl = wv * 16 + colb;
        const bf16* xp = x2 + (row0 + rl) * CDIM + quad * 48;
        bf16x8 raw[6];
        float s = 0.f, sq = 0.f;
        #pragma unroll
        for (int j = 0; j < 6; ++j) {
            raw[j] = *(const bf16x8*)(xp + j * 8);
            #pragma unroll
            for (int e = 0; e < 8; ++e) { float f = (float)raw[j][e]; s += f; sq += f * f; }
        }
        s += __shfl_xor(s, 16); sq += __shfl_xor(sq, 16);
        s += __shfl_xor(s, 32); sq += __shfl_xor(sq, 32);
        float mean = s * (1.0f / 192.0f);
        float var  = sq * (1.0f / 192.0f) - mean * mean;
        float rstd = rsqrtf(fmaxf(var, 0.0f) + 1e-5f);
        #pragma unroll
        for (int j = 0; j < 6; ++j) {
            bf16x8 o;
            #pragma unroll
            for (int e = 0; e < 8; ++e) {
                int col = quad * 48 + j * 8 + e;
                o[e] = (__bf16)(((float)raw[j][e] - mean) * rstd * g[col] + b[col]);
            }
            *(bf16x8*)(&sX[rl * 200 + quad * 48 + j * 8]) = o;
        }
    }
    // no barrier needed: each wave reads only its own 16 rows of sX.

    floatx4 oacc[12] = {};
    for (int c = 0; c < 3; ++c) {
        floatx4 hacc[16] = {};
        for (int k0 = 0; k0 < 192; k0 += 32) {
            __syncthreads();
            {   // stage w1 rows c*256..+256, k-cols k0..k0+32
                const bf16* wp = w1 + ((long)(c * 256 + tid)) * 192 + k0;
                #pragma unroll
                for (int j = 0; j < 4; ++j)
                    *(uint4*)(&sW[tid * 40 + j * 8]) = *(const uint4*)(wp + j * 8);
            }
            __syncthreads();
            bf16x8 aF = *(const bf16x8*)(&sX[(wv * 16 + colb) * 200 + k0 + quad * 8]);
            #pragma unroll
            for (int nt = 0; nt < 16; ++nt) {
                bf16x8 bF = *(const bf16x8*)(&sW[(nt * 16 + colb) * 40 + quad * 8]);
                hacc[nt] = __builtin_amdgcn_mfma_f32_16x16x32_bf16(aF, bF, hacc[nt], 0, 0, 0);
            }
        }
        // gelu -> sH (wave-local rows)
        #pragma unroll
        for (int nt = 0; nt < 16; ++nt) {
            float bv = b1[c * 256 + nt * 16 + colb];
            #pragma unroll
            for (int r = 0; r < 4; ++r) {
                float val = hacc[nt][r] + bv;
                float gl = 0.5f * val * (1.0f + erf_as(val * 0.70710678118654752f));
                sH[(wv * 16 + quad * 4 + r) * 264 + nt * 16 + colb] = __float2bfloat16(gl);
            }
        }
        for (int kk = 0; kk < 256; kk += 32) {
            __syncthreads();
            {   // stage w2: 192 rows x 32 k
                #pragma unroll
                for (int i = 0; i < 3; ++i) {
                    int v = tid + i * 256;
                    int n = v >> 2, j = (v & 3) << 3;
                    *(uint4*)(&sW[n * 40 + j]) =
                        *(const uint4*)(w2 + (long)n * 768 + c * 256 + kk + j);
                }
            }
            __syncthreads();
            bf16x8 aF = *(const bf16x8*)(&sH[(wv * 16 + colb) * 264 + kk + quad * 8]);
            #pragma unroll
            for (int ot = 0; ot < 12; ++ot) {
                bf16x8 bF = *(const bf16x8*)(&sW[(ot * 16 + colb) * 40 + quad * 8]);
                oacc[ot] = __builtin_amdgcn_mfma_f32_16x16x32_bf16(aF, bF, oacc[ot], 0, 0, 0);
            }
        }
    }
    // ---- epilogue: out(natural) = oacc + b2 + x2
    #pragma unroll
    for (int ot = 0; ot < 12; ++ot) {
        float bv = b2[ot * 16 + colb];
        #pragma unroll
        for (int r = 0; r < 4; ++r) {
            long rl = row0 + wv * 16 + quad * 4 + r;
            int col = ot * 16 + colb;
            int wi = wi_base + (int)(rl >> 7), n = (int)rl & 127;
            float val = oacc[ot][r] + bv + (float)x2[rl * CDIM + col];
            out[nat_index(wi, n, col)] = val;
        }
    }
}

// ---------------------------------------------------------------------------
extern "C" void kernel_launch(void* const* d_in, const int* in_sizes, int n_in,
                              void* d_out, int out_size, void* d_ws, size_t ws_size,
                              hipStream_t stream) {
    const float* x      = (const float*)d_in[0];
    const float* n1g    = (const float*)d_in[1];
    const float* n1b    = (const float*)d_in[2];
    const float* qkv_w  = (const float*)d_in[3];
    const float* qkv_b  = (const float*)d_in[4];
    const float* btab   = (const float*)d_in[5];
    const float* proj_w = (const float*)d_in[6];
    const float* proj_b = (const float*)d_in[7];
    const float* n2g    = (const float*)d_in[8];
    const float* n2b    = (const float*)d_in[9];
    const float* fc1_w  = (const float*)d_in[10];
    const float* fc1_b  = (const float*)d_in[11];
    const float* fc2_w  = (const float*)d_in[12];
    const float* fc2_b  = (const float*)d_in[13];
    float* outp = (float*)d_out;

    char* ws = (char*)d_ws;
    // bf16 weight block at start of ws
    bf16* wts   = (bf16*)ws;
    bf16* wqkv  = wts;
    bf16* wproj = wts + 110592;
    bf16* w1    = wts + 147456;
    bf16* w2    = wts + 294912;
    const size_t WBYTES = 442368UL * 2;    // 884736

    // slab sizing: 4 slots of S*128*192 bf16 + weights must fit ws
    const size_t per_win = 4UL * 128 * CDIM * 2;
    int S = N_WINDOWS;
    while (S > 64 && (size_t)S * per_win + WBYTES > ws_size) S >>= 1;

    char* sl = ws + WBYTES;
    const size_t SLOT = (size_t)S * 128 * CDIM * 2;
    bf16* bufA = (bf16*)(sl);               // ln1 out -> attn_out
    bf16* qb   = (bf16*)(sl + SLOT);        // q -> x2
    bf16* kb   = (bf16*)(sl + 2 * SLOT);    // k
    bf16* vb   = (bf16*)(sl + 3 * SLOT);    // v (transposed)
    bf16* x2   = qb;

    convert_weights<<<216, 256, 0, stream>>>(qkv_w, proj_w, fc1_w, fc2_w, wts);

    for (int s0 = 0; s0 < N_WINDOWS; s0 += S) {
        ln_kernel<<<S * 32, 256, 0, stream>>>(x, n1g, n1b, bufA, s0);
        gemm_bt<EpiQKV><<<dim3(S, 9), 256, 0, stream>>>(bufA, wqkv, 192, EpiQKV{qkv_b, qb, kb, vb});
        attn_kernel<<<S * 6, 256, 0, stream>>>(qb, kb, vb, btab, bufA);
        gemm_bt<EpiProj><<<dim3(S, 3), 256, 0, stream>>>(bufA, wproj, 192, EpiProj{proj_b, x, x2, s0});
        mlp_kernel<<<S * 2, 256, 0, stream>>>(x2, n2g, n2b, w1, fc1_b, w2, fc2_b, outp, s0);
    }
}